// Round 13
// baseline (39.508 us; speedup 1.0000x reference)
//
#include <hip/hip_runtime.h>
#include <math.h>

#define M       32
#define IDIM    64
#define DIN     68
#define HDIM    128

// ws float offsets. A4 and Wvo4 are CONTIGUOUS (staged to LDS as 34x1KB chunks).
// A4:   ws[((i4*DIN + d) << 2) + k]            = A[4*i4+k][d]    (i4<16, d<68, k<4)
// Wvo4: ws[WS_WVO4 + ((d4*IDIM + j) << 2) + k] = Wvo[4*d4+k][j]  (d4<17, j<64, k<4)
#define WS_A4     0        // 4352 floats
#define WS_WVO4   4352     // 4352 floats
#define WS_U0     8704     // 68
#define WS_G      8772     // 64
#define WS_C0     8836     // 1
#define WS_OUTB   8840     // 64
#define WS_FLOATS 8904

#define CST_FLOATS 8704    // A4+Wvo4 in LDS: 34816 B = 34 chunks of 1KB
#define CST_WVO    4352

// DPP helpers (VALU pipe, no DS). CTRL must be an immediate -> template.
template <int CTRL>
__device__ __forceinline__ float dpp_add(float x) {
  int t = __builtin_amdgcn_update_dpp(0, __float_as_int(x), CTRL, 0xF, 0xF, true);
  return x + __int_as_float(t);
}
__device__ __forceinline__ float red4(float x) {   // sum over aligned quad
  x = dpp_add<0xB1>(x);    // quad_perm xor1 (direction-free)
  x = dpp_add<0x4E>(x);    // quad_perm xor2 (direction-free)
  return x;
}
__device__ __forceinline__ float red16(float x) {  // sum over 16-lane group
  x = dpp_add<0xB1>(x);
  x = dpp_add<0x4E>(x);
  x = dpp_add<0x124>(x);   // row_ror:4  (any rotation direction OK for 16-sum)
  x = dpp_add<0x128>(x);   // row_ror:8
  return x;
}
// NOTE (R12 lesson): an 8-group DPP reduce via row_ror:4 is DIRECTION-
// DEPENDENT (lane0 may receive quad3, not quad1) -> corrupted weights.
// Only quad_perm (red4) and full-row (red16) reductions are direction-safe.

// 4 threads per output element, each dotting 32 of 128 h's, DPP quad-reduce.
#define SEG_A   0
#define SEG_W   17408
#define SEG_U0  34816
#define SEG_G   35088
#define SEG_OB  35344
#define SEG_C0  35600
#define PRE_T   35601

__global__ __launch_bounds__(256)
void ga_precompute(const float* __restrict__ Wq, const float* __restrict__ bq,
                   const float* __restrict__ Wk, const float* __restrict__ bk,
                   const float* __restrict__ Wv, const float* __restrict__ bv,
                   const float* __restrict__ Wo, const float* __restrict__ bo,
                   float* __restrict__ ws) {
  int t = blockIdx.x * 256 + threadIdx.x;
  if (t >= PRE_T) return;
  const float4* Wq4 = (const float4*)Wq;   // [64][32]
  const float4* Wk4 = (const float4*)Wk;   // [68][32]
  const float4* Wv4 = (const float4*)Wv;   // [68][32]
  const float4* bq4 = (const float4*)bq;   // [32]
  const float4* bk4 = (const float4*)bk;   // [32]
  const int sub = t & 3;
  const int h4b = sub * 8;                 // float4-chunk base of this thread's h-range

  if (t < SEG_W) {                         // A4
    int e = t >> 2;
    int k = e & 3, rem = e >> 2;
    int d = rem % DIN, i4 = rem / DIN;
    int i = i4 * 4 + k;
    float acc = 0.f;
    #pragma unroll
    for (int hh = 0; hh < 8; ++hh) {
      float4 a = Wq4[i*32 + h4b + hh], b = Wk4[d*32 + h4b + hh];
      acc = fmaf(a.x, b.x, acc); acc = fmaf(a.y, b.y, acc);
      acc = fmaf(a.z, b.z, acc); acc = fmaf(a.w, b.w, acc);
    }
    acc = red4(acc);
    if (sub == 0) ws[WS_A4 + e] = acc;
  } else if (t < SEG_U0) {                 // Wvo4
    int e = (t - SEG_W) >> 2;
    int k = e & 3, rem = e >> 2;
    int j = rem & 63, d4 = rem >> 6;
    int d = d4 * 4 + k;
    float acc = 0.f;
    #pragma unroll
    for (int hh = 0; hh < 8; ++hh) {
      float4 v = Wv4[d*32 + h4b + hh];
      int h = (h4b + hh) * 4;
      acc = fmaf(v.x, Wo[(h    )*IDIM + j], acc);
      acc = fmaf(v.y, Wo[(h + 1)*IDIM + j], acc);
      acc = fmaf(v.z, Wo[(h + 2)*IDIM + j], acc);
      acc = fmaf(v.w, Wo[(h + 3)*IDIM + j], acc);
    }
    acc = red4(acc);
    if (sub == 0) ws[WS_WVO4 + e] = acc;
  } else if (t < SEG_G) {                  // u0
    int d = (t - SEG_U0) >> 2;
    float acc = 0.f;
    #pragma unroll
    for (int hh = 0; hh < 8; ++hh) {
      float4 a = Wk4[d*32 + h4b + hh], b = bq4[h4b + hh];
      acc = fmaf(a.x, b.x, acc); acc = fmaf(a.y, b.y, acc);
      acc = fmaf(a.z, b.z, acc); acc = fmaf(a.w, b.w, acc);
    }
    acc = red4(acc);
    if (sub == 0) ws[WS_U0 + d] = acc;
  } else if (t < SEG_OB) {                 // g
    int i = (t - SEG_G) >> 2;
    float acc = 0.f;
    #pragma unroll
    for (int hh = 0; hh < 8; ++hh) {
      float4 a = Wq4[i*32 + h4b + hh], b = bk4[h4b + hh];
      acc = fmaf(a.x, b.x, acc); acc = fmaf(a.y, b.y, acc);
      acc = fmaf(a.z, b.z, acc); acc = fmaf(a.w, b.w, acc);
    }
    acc = red4(acc);
    if (sub == 0) ws[WS_G + i] = acc;
  } else if (t < SEG_C0) {                 // outb
    int j = (t - SEG_OB) >> 2;
    float acc = 0.f;
    #pragma unroll
    for (int hh = 0; hh < 8; ++hh) {
      int h = (h4b + hh) * 4;
      acc = fmaf(bv[h    ], Wo[(h    )*IDIM + j], acc);
      acc = fmaf(bv[h + 1], Wo[(h + 1)*IDIM + j], acc);
      acc = fmaf(bv[h + 2], Wo[(h + 2)*IDIM + j], acc);
      acc = fmaf(bv[h + 3], Wo[(h + 3)*IDIM + j], acc);
    }
    acc = red4(acc);
    if (sub == 0) ws[WS_OUTB + j] = acc + bo[j];
  } else {                                 // c0
    float acc = 0.f;
    for (int h = 0; h < HDIM; ++h) acc = fmaf(bq[h], bk[h], acc);
    ws[WS_C0] = acc;
  }
}

// 512 threads = 8 waves, one row per wave (measured-best R8 structure).
// glls split A-group (K=0..2) / W-group (K=3..4): first barrier waits only
// the A panel (vmcnt(12): wave0/1 have 15 outstanding -> retire 3 incl chunk
// 16/17; waves2-7 have 14 -> retire their 2 A-chunks). Wvo published by a
// second barrier after phase 1 (vmcnt(10) retires every wave's W-glls,
// monotone-safe vs compiler-inserted waits). launch_bounds(512,4): VGPR cap
// 64, 4 blocks/CU (32 waves, LDS 38.9KB).
__global__ __launch_bounds__(512, 4)
void ga_main(const float* __restrict__ ego,
             const float* __restrict__ nz,
             const float* __restrict__ rp,
             const int*   __restrict__ mask,
             const float* __restrict__ ws,
             float* __restrict__ out) {
  __shared__ float cst   [CST_FLOATS];  // 34816 B
  __shared__ float u_lds [8 * 64];      // 2048 B
  __shared__ float fb_lds[8 * 64];      // 2048 B

  const int tid  = threadIdx.x;
  const int wave = tid >> 6;
  const int lane = tid & 63;
  const int t4   = lane >> 4;
  const int l    = lane & 15;
  const int row  = __builtin_amdgcn_readfirstlane(blockIdx.x * 8 + wave);

  // ---- const staging: global_load_lds, 34 chunks of 1KB. A first, then W. ----
  #define GLL(K) do { int c = wave + 8*(K); if (c < 34)                         \
    __builtin_amdgcn_global_load_lds(                                           \
      (const __attribute__((address_space(1))) void*)(ws + c*256 + lane*4),     \
      (__attribute__((address_space(3))) void*)(cst + c*256), 16, 0, 0); } while(0)
  GLL(0); GLL(1); GLL(2);                 // chunks wave, wave+8, wave+16
  __builtin_amdgcn_sched_barrier(0);      // keep these oldest
  GLL(3); GLL(4);                         // chunks wave+24, wave+32
  #undef GLL
  __builtin_amdgcn_sched_barrier(0);

  // ---- per-row loads (youngest: stay in flight across both barriers) ----
  const float4* zsrc4 = (const float4*)(nz + (size_t)row * (M * IDIM));
  float4 z0 = zsrc4[0*64 + lane], z1 = zsrc4[1*64 + lane];
  float4 z2 = zsrc4[2*64 + lane], z3 = zsrc4[3*64 + lane];
  float4 z4 = zsrc4[4*64 + lane], z5 = zsrc4[5*64 + lane];
  float4 z6 = zsrc4[6*64 + lane], z7 = zsrc4[7*64 + lane];
  const float4* rpsrc = (const float4*)(rp + (size_t)row * (M * 4));
  const float4 rpa = rpsrc[4 * (lane & 7) + t4];   // rp row for m=4*(l&7)+t4
  const int    mreg = mask[row * M + (lane & 31)];

  __builtin_amdgcn_sched_barrier(0);
  asm volatile("s_waitcnt vmcnt(12)" ::: "memory");   // A-panel glls retired
  __builtin_amdgcn_s_barrier();
  asm volatile("" ::: "memory");

  // ---- phase 1: u[d] = ego @ A + u0, lane = d (A4 from LDS, b128) ----
  const float* egoR = ego + (size_t)row * IDIM;   // wave-uniform -> s_loads
  {
    float ua0 = 0.f, ua1 = 0.f, ua2 = 0.f, ua3 = 0.f;
    #pragma unroll 8
    for (int i4 = 0; i4 < 16; ++i4) {
      const float4 av = *(const float4*)&cst[(i4 * DIN + lane) << 2];
      ua0 = fmaf(egoR[i4 * 4],     av.x, ua0);
      ua1 = fmaf(egoR[i4 * 4 + 1], av.y, ua1);
      ua2 = fmaf(egoR[i4 * 4 + 2], av.z, ua2);
      ua3 = fmaf(egoR[i4 * 4 + 3], av.w, ua3);
    }
    u_lds[wave * 64 + lane] = ((ua0 + ua1) + (ua2 + ua3)) + ws[WS_U0 + lane];
  }
  // tail u[64..67]: DPP reduce + readlane; fold into rpdot HERE (uh/rpa die)
  float rpdot;
  {
    const float4 av = *(const float4*)&cst[(l * DIN + IDIM + t4) << 2];
    float pt = egoR[l * 4] * av.x;
    pt = fmaf(egoR[l * 4 + 1], av.y, pt);
    pt = fmaf(egoR[l * 4 + 2], av.z, pt);
    pt = fmaf(egoR[l * 4 + 3], av.w, pt);
    pt = red16(pt);
    int pti = __float_as_int(pt);
    float uh0 = __int_as_float(__builtin_amdgcn_readlane(pti, 0))  + ws[WS_U0 + 64];
    float uh1 = __int_as_float(__builtin_amdgcn_readlane(pti, 16)) + ws[WS_U0 + 65];
    float uh2 = __int_as_float(__builtin_amdgcn_readlane(pti, 32)) + ws[WS_U0 + 66];
    float uh3 = __int_as_float(__builtin_amdgcn_readlane(pti, 48)) + ws[WS_U0 + 67];
    rpdot = fmaf(rpa.w, uh3, fmaf(rpa.z, uh2, fmaf(rpa.y, uh1, rpa.x * uh0)));
  }
  // cterm = ego.g + c0
  float cterm;
  {
    float pc = egoR[lane] * ws[WS_G + lane];
    pc = red16(pc);
    pc += __shfl_xor(pc, 16);
    pc += __shfl_xor(pc, 32);
    cterm = pc + ws[WS_C0];
  }

  // ---- second barrier: publish Wvo panel (W-glls retired; u_lds synced) ----
  asm volatile("s_waitcnt vmcnt(10) lgkmcnt(0)" ::: "memory");
  __builtin_amdgcn_s_barrier();
  asm volatile("" ::: "memory");

  // ---- phase 2: scores in (it,t4) space ----
  const float4 u4 = *(const float4*)&u_lds[wave * 64 + l * 4];
  const unsigned int mbits  = (unsigned int)__ballot(mreg != 0);
  const unsigned int mshift = mbits >> t4;   // bit 4*it = mask of m=4*it+t4

  #define SC(IT, Z) float s##IT; {                                        \
    float p = (Z).x * u4.x;                                               \
    p = fmaf((Z).y, u4.y, p);                                             \
    p = fmaf((Z).z, u4.z, p);                                             \
    p = fmaf((Z).w, u4.w, p);                                             \
    p += (l == (IT)) ? rpdot : 0.f;                                       \
    p = red16(p);                                                         \
    s##IT = ((mshift >> (4*(IT))) & 1u)                                   \
          ? (p + cterm) * 0.088388347648318447f : -1e9f; }
  SC(0, z0) SC(1, z1) SC(2, z2) SC(3, z3)
  SC(4, z4) SC(5, z5) SC(6, z6) SC(7, z7)
  #undef SC

  // softmax over 32 m's: 8 in-lane + cross-group (xor16, xor32)
  float mx = fmaxf(fmaxf(fmaxf(s0, s1), fmaxf(s2, s3)),
                   fmaxf(fmaxf(s4, s5), fmaxf(s6, s7)));
  mx = fmaxf(mx, __shfl_xor(mx, 16));
  mx = fmaxf(mx, __shfl_xor(mx, 32));
  float e0 = __expf(s0 - mx), e1 = __expf(s1 - mx);
  float e2 = __expf(s2 - mx), e3 = __expf(s3 - mx);
  float e4 = __expf(s4 - mx), e5 = __expf(s5 - mx);
  float e6 = __expf(s6 - mx), e7 = __expf(s7 - mx);
  float se = ((e0 + e1) + (e2 + e3)) + ((e4 + e5) + (e6 + e7));
  se += __shfl_xor(se, 16);
  se += __shfl_xor(se, 32);
  const float rse = __builtin_amdgcn_rcpf(se);
  const float w0 = e0 * rse, w1 = e1 * rse, w2 = e2 * rse, w3 = e3 * rse;
  const float w4 = e4 * rse, w5 = e5 * rse, w6 = e6 * rse, w7 = e7 * rse;

  // ---- phase 3: fbar[4l+k] — weights already in-lane, no broadcast ----
  float p40 = 0.f, p41 = 0.f, p42 = 0.f, p43 = 0.f;
  #define FB(W, Z) do {                                                   \
    p40 = fmaf((W), (Z).x, p40);                                          \
    p41 = fmaf((W), (Z).y, p41);                                          \
    p42 = fmaf((W), (Z).z, p42);                                          \
    p43 = fmaf((W), (Z).w, p43);                                          \
  } while (0);
  FB(w0, z0) FB(w1, z1) FB(w2, z2) FB(w3, z3)
  FB(w4, z4) FB(w5, z5) FB(w6, z6) FB(w7, z7)
  #undef FB
  p40 += __shfl_xor(p40, 16);  p40 += __shfl_xor(p40, 32);
  p41 += __shfl_xor(p41, 16);  p41 += __shfl_xor(p41, 32);
  p42 += __shfl_xor(p42, 16);  p42 += __shfl_xor(p42, 32);
  p43 += __shfl_xor(p43, 16);  p43 += __shfl_xor(p43, 32);
  if (lane < 16) {
    float4 fv; fv.x = p40; fv.y = p41; fv.z = p42; fv.w = p43;
    *(float4*)&fb_lds[wave * 64 + l * 4] = fv;
  }

  // rp tail: fbar[64+k] = sum_m w_m*rp[m][k]. This lane's rpa row m=4*(l&7)+t4
  // pairs with its own w_{l&7}; each m counted twice -> fold 0.5 into weight.
  float wsel;
  {
    float a0 = (l & 1) ? w1 : w0, a1 = (l & 1) ? w3 : w2;
    float a2 = (l & 1) ? w5 : w4, a3 = (l & 1) ? w7 : w6;
    float b0 = (l & 2) ? a1 : a0, b1 = (l & 2) ? a3 : a2;
    wsel = 0.5f * ((l & 4) ? b1 : b0);
  }
  float pr0 = wsel * rpa.x, pr1 = wsel * rpa.y;
  float pr2 = wsel * rpa.z, pr3 = wsel * rpa.w;
  pr0 = red16(pr0); pr0 += __shfl_xor(pr0, 16); pr0 += __shfl_xor(pr0, 32);
  pr1 = red16(pr1); pr1 += __shfl_xor(pr1, 16); pr1 += __shfl_xor(pr1, 32);
  pr2 = red16(pr2); pr2 += __shfl_xor(pr2, 16); pr2 += __shfl_xor(pr2, 32);
  pr3 = red16(pr3); pr3 += __shfl_xor(pr3, 16); pr3 += __shfl_xor(pr3, 32);

  asm volatile("" ::: "memory");   // fb_lds write -> read

  // ---- phase 4: out[j] = fbar @ Wvo + outb, lane = j (Wvo4 from LDS) ----
  float oa0 = 0.f, oa1 = 0.f, oa2 = 0.f, oa3 = 0.f;
  #pragma unroll 8
  for (int d4 = 0; d4 < 16; ++d4) {
    const float4 wv = *(const float4*)&cst[CST_WVO + ((d4 * IDIM + lane) << 2)];
    const float4 fv = *(const float4*)&fb_lds[wave * 64 + d4 * 4]; // broadcast
    oa0 = fmaf(fv.x, wv.x, oa0);
    oa1 = fmaf(fv.y, wv.y, oa1);
    oa2 = fmaf(fv.z, wv.z, oa2);
    oa3 = fmaf(fv.w, wv.w, oa3);
  }
  {
    const float4 wv = *(const float4*)&cst[CST_WVO + ((16 * IDIM + lane) << 2)];
    oa0 = fmaf(pr0, wv.x, oa0);
    oa1 = fmaf(pr1, wv.y, oa1);
    oa2 = fmaf(pr2, wv.z, oa2);
    oa3 = fmaf(pr3, wv.w, oa3);
  }
  out[(size_t)row * IDIM + lane] = ((oa0 + oa1) + (oa2 + oa3)) + ws[WS_OUTB + lane];
}

extern "C" void kernel_launch(void* const* d_in, const int* in_sizes, int n_in,
                              void* d_out, int out_size, void* d_ws, size_t ws_size,
                              hipStream_t stream) {
  const float* ego = (const float*)d_in[0];
  const float* nz  = (const float*)d_in[1];
  const float* rp  = (const float*)d_in[2];
  const int*   mk  = (const int*)d_in[3];
  const float* Wq  = (const float*)d_in[4];
  const float* bq  = (const float*)d_in[5];
  const float* Wk  = (const float*)d_in[6];
  const float* bk  = (const float*)d_in[7];
  const float* Wv  = (const float*)d_in[8];
  const float* bv  = (const float*)d_in[9];
  const float* Wo  = (const float*)d_in[10];
  const float* bo  = (const float*)d_in[11];
  float* ws = (float*)d_ws;   // needs WS_FLOATS*4 = 35616 bytes
  float* o  = (float*)d_out;

  const int nrows = in_sizes[0] / IDIM;   // 16384

  ga_precompute<<<(PRE_T + 255) / 256, 256, 0, stream>>>(
      Wq, bq, Wk, bk, Wv, bv, Wo, bo, ws);
  ga_main<<<nrows / 8, 512, 0, stream>>>(ego, nz, rp, mk, ws, o);
}

// Round 14
// 38.240 us; speedup vs baseline: 1.0332x; 1.0332x over previous
//
#include <hip/hip_runtime.h>
#include <math.h>

#define M       32
#define IDIM    64
#define DIN     68
#define HDIM    128

// ws float offsets. A4 and Wvo4 are CONTIGUOUS (staged to LDS as 34x1KB chunks).
// A4:   ws[((i4*DIN + d) << 2) + k]            = A[4*i4+k][d]    (i4<16, d<68, k<4)
// Wvo4: ws[WS_WVO4 + ((d4*IDIM + j) << 2) + k] = Wvo[4*d4+k][j]  (d4<17, j<64, k<4)
#define WS_A4     0        // 4352 floats
#define WS_WVO4   4352     // 4352 floats
#define WS_U0     8704     // 68
#define WS_G      8772     // 64
#define WS_C0     8836     // 1
#define WS_OUTB   8840     // 64
#define WS_FLOATS 8904

#define CST_FLOATS 8704    // A4+Wvo4 in LDS: 34816 B = 34 chunks of 1KB
#define CST_WVO    4352

// DPP helpers (VALU pipe, no DS). CTRL must be an immediate -> template.
template <int CTRL>
__device__ __forceinline__ float dpp_add(float x) {
  int t = __builtin_amdgcn_update_dpp(0, __float_as_int(x), CTRL, 0xF, 0xF, true);
  return x + __int_as_float(t);
}
__device__ __forceinline__ float red4(float x) {   // sum over aligned quad
  x = dpp_add<0xB1>(x);    // quad_perm xor1 (direction-free)
  x = dpp_add<0x4E>(x);    // quad_perm xor2 (direction-free)
  return x;
}
__device__ __forceinline__ float red16(float x) {  // sum over 16-lane group
  x = dpp_add<0xB1>(x);
  x = dpp_add<0x4E>(x);
  x = dpp_add<0x124>(x);   // row_ror:4  (any rotation direction OK for 16-sum)
  x = dpp_add<0x128>(x);   // row_ror:8
  return x;
}
// NOTE (R12 lesson): an 8-group DPP reduce via row_ror:4 is DIRECTION-
// DEPENDENT (lane0 may receive quad3, not quad1) -> corrupted weights.
// Only quad_perm (red4) and full-row (red16) reductions are direction-safe.

// 4 threads per output element, each dotting 32 of 128 h's, DPP quad-reduce.
#define SEG_A   0
#define SEG_W   17408
#define SEG_U0  34816
#define SEG_G   35088
#define SEG_OB  35344
#define SEG_C0  35600
#define PRE_T   35601

__global__ __launch_bounds__(256)
void ga_precompute(const float* __restrict__ Wq, const float* __restrict__ bq,
                   const float* __restrict__ Wk, const float* __restrict__ bk,
                   const float* __restrict__ Wv, const float* __restrict__ bv,
                   const float* __restrict__ Wo, const float* __restrict__ bo,
                   float* __restrict__ ws) {
  int t = blockIdx.x * 256 + threadIdx.x;
  if (t >= PRE_T) return;
  const float4* Wq4 = (const float4*)Wq;   // [64][32]
  const float4* Wk4 = (const float4*)Wk;   // [68][32]
  const float4* Wv4 = (const float4*)Wv;   // [68][32]
  const float4* bq4 = (const float4*)bq;   // [32]
  const float4* bk4 = (const float4*)bk;   // [32]
  const int sub = t & 3;
  const int h4b = sub * 8;                 // float4-chunk base of this thread's h-range

  if (t < SEG_W) {                         // A4
    int e = t >> 2;
    int k = e & 3, rem = e >> 2;
    int d = rem % DIN, i4 = rem / DIN;
    int i = i4 * 4 + k;
    float acc = 0.f;
    #pragma unroll
    for (int hh = 0; hh < 8; ++hh) {
      float4 a = Wq4[i*32 + h4b + hh], b = Wk4[d*32 + h4b + hh];
      acc = fmaf(a.x, b.x, acc); acc = fmaf(a.y, b.y, acc);
      acc = fmaf(a.z, b.z, acc); acc = fmaf(a.w, b.w, acc);
    }
    acc = red4(acc);
    if (sub == 0) ws[WS_A4 + e] = acc;
  } else if (t < SEG_U0) {                 // Wvo4
    int e = (t - SEG_W) >> 2;
    int k = e & 3, rem = e >> 2;
    int j = rem & 63, d4 = rem >> 6;
    int d = d4 * 4 + k;
    float acc = 0.f;
    #pragma unroll
    for (int hh = 0; hh < 8; ++hh) {
      float4 v = Wv4[d*32 + h4b + hh];
      int h = (h4b + hh) * 4;
      acc = fmaf(v.x, Wo[(h    )*IDIM + j], acc);
      acc = fmaf(v.y, Wo[(h + 1)*IDIM + j], acc);
      acc = fmaf(v.z, Wo[(h + 2)*IDIM + j], acc);
      acc = fmaf(v.w, Wo[(h + 3)*IDIM + j], acc);
    }
    acc = red4(acc);
    if (sub == 0) ws[WS_WVO4 + e] = acc;
  } else if (t < SEG_G) {                  // u0
    int d = (t - SEG_U0) >> 2;
    float acc = 0.f;
    #pragma unroll
    for (int hh = 0; hh < 8; ++hh) {
      float4 a = Wk4[d*32 + h4b + hh], b = bq4[h4b + hh];
      acc = fmaf(a.x, b.x, acc); acc = fmaf(a.y, b.y, acc);
      acc = fmaf(a.z, b.z, acc); acc = fmaf(a.w, b.w, acc);
    }
    acc = red4(acc);
    if (sub == 0) ws[WS_U0 + d] = acc;
  } else if (t < SEG_OB) {                 // g
    int i = (t - SEG_G) >> 2;
    float acc = 0.f;
    #pragma unroll
    for (int hh = 0; hh < 8; ++hh) {
      float4 a = Wq4[i*32 + h4b + hh], b = bk4[h4b + hh];
      acc = fmaf(a.x, b.x, acc); acc = fmaf(a.y, b.y, acc);
      acc = fmaf(a.z, b.z, acc); acc = fmaf(a.w, b.w, acc);
    }
    acc = red4(acc);
    if (sub == 0) ws[WS_G + i] = acc;
  } else if (t < SEG_C0) {                 // outb
    int j = (t - SEG_OB) >> 2;
    float acc = 0.f;
    #pragma unroll
    for (int hh = 0; hh < 8; ++hh) {
      int h = (h4b + hh) * 4;
      acc = fmaf(bv[h    ], Wo[(h    )*IDIM + j], acc);
      acc = fmaf(bv[h + 1], Wo[(h + 1)*IDIM + j], acc);
      acc = fmaf(bv[h + 2], Wo[(h + 2)*IDIM + j], acc);
      acc = fmaf(bv[h + 3], Wo[(h + 3)*IDIM + j], acc);
    }
    acc = red4(acc);
    if (sub == 0) ws[WS_OUTB + j] = acc + bo[j];
  } else {                                 // c0
    float acc = 0.f;
    for (int h = 0; h < HDIM; ++h) acc = fmaf(bq[h], bk[h], acc);
    ws[WS_C0] = acc;
  }
}

// MEASURED-BEST configuration (R8: 37.8us total; reproduced 38.4us R11).
// 512 threads = 8 waves, one row per wave, grid 2048. A4+Wvo4 (34KB) staged
// to LDS via global_load_lds (single counted vmcnt(10); the 10 per-row loads
// stay in flight across the barrier). Lane space: t4=lane>>4 (m-subgroup),
// l=lane&15 (d-chunk); z_it = feats[m=4*it+t4][4l..4l+3]. Scores/softmax/
// weights per-lane in (it,t4) space; all 4-level reductions are DPP (VALU).
// launch_bounds(512,4): VGPR cap 64 -> 4 blocks/CU (32 waves, LDS 38.9KB).
// Falsified alternatives: R9 2-row persistent pipeline (+0.7us), R10 Wvo->L2
// +readlane rebalance (+1.7us), R13 split A/W barriers (+1.1us).
__global__ __launch_bounds__(512, 4)
void ga_main(const float* __restrict__ ego,
             const float* __restrict__ nz,
             const float* __restrict__ rp,
             const int*   __restrict__ mask,
             const float* __restrict__ ws,
             float* __restrict__ out) {
  __shared__ float cst   [CST_FLOATS];  // 34816 B
  __shared__ float u_lds [8 * 64];      // 2048 B
  __shared__ float fb_lds[8 * 64];      // 2048 B

  const int tid  = threadIdx.x;
  const int wave = tid >> 6;
  const int lane = tid & 63;
  const int t4   = lane >> 4;
  const int l    = lane & 15;
  const int row  = __builtin_amdgcn_readfirstlane(blockIdx.x * 8 + wave);

  // ---- const staging: global_load_lds, 34 chunks of 1KB (oldest in vmcnt) ----
  #define GLL(K) do { int c = wave + 8*(K); if (c < 34)                         \
    __builtin_amdgcn_global_load_lds(                                           \
      (const __attribute__((address_space(1))) void*)(ws + c*256 + lane*4),     \
      (__attribute__((address_space(3))) void*)(cst + c*256), 16, 0, 0); } while(0)
  GLL(0); GLL(1); GLL(2); GLL(3); GLL(4);
  #undef GLL
  __builtin_amdgcn_sched_barrier(0);

  // ---- per-row loads (younger: stay in flight across barrier): 10 VMEM ----
  const float4* zsrc4 = (const float4*)(nz + (size_t)row * (M * IDIM));
  float4 z0 = zsrc4[0*64 + lane], z1 = zsrc4[1*64 + lane];
  float4 z2 = zsrc4[2*64 + lane], z3 = zsrc4[3*64 + lane];
  float4 z4 = zsrc4[4*64 + lane], z5 = zsrc4[5*64 + lane];
  float4 z6 = zsrc4[6*64 + lane], z7 = zsrc4[7*64 + lane];
  const float4* rpsrc = (const float4*)(rp + (size_t)row * (M * 4));
  const float4 rpa = rpsrc[4 * (lane & 7) + t4];   // rp row for m=4*(l&7)+t4
  const int    mreg = mask[row * M + (lane & 31)];

  __builtin_amdgcn_sched_barrier(0);
  asm volatile("s_waitcnt vmcnt(10)" ::: "memory");   // glls done; row loads fly
  __builtin_amdgcn_s_barrier();
  asm volatile("" ::: "memory");

  // ---- phase 1: u[d] = ego @ A + u0, lane = d (A4 from LDS, b128) ----
  const float* egoR = ego + (size_t)row * IDIM;   // wave-uniform -> s_loads
  {
    float ua0 = 0.f, ua1 = 0.f, ua2 = 0.f, ua3 = 0.f;
    #pragma unroll 8
    for (int i4 = 0; i4 < 16; ++i4) {
      const float4 av = *(const float4*)&cst[(i4 * DIN + lane) << 2];
      ua0 = fmaf(egoR[i4 * 4],     av.x, ua0);
      ua1 = fmaf(egoR[i4 * 4 + 1], av.y, ua1);
      ua2 = fmaf(egoR[i4 * 4 + 2], av.z, ua2);
      ua3 = fmaf(egoR[i4 * 4 + 3], av.w, ua3);
    }
    u_lds[wave * 64 + lane] = ((ua0 + ua1) + (ua2 + ua3)) + ws[WS_U0 + lane];
  }
  // tail u[64..67]: DPP reduce + readlane; fold into rpdot HERE (uh/rpa die)
  float rpdot;
  {
    const float4 av = *(const float4*)&cst[(l * DIN + IDIM + t4) << 2];
    float pt = egoR[l * 4] * av.x;
    pt = fmaf(egoR[l * 4 + 1], av.y, pt);
    pt = fmaf(egoR[l * 4 + 2], av.z, pt);
    pt = fmaf(egoR[l * 4 + 3], av.w, pt);
    pt = red16(pt);
    int pti = __float_as_int(pt);
    float uh0 = __int_as_float(__builtin_amdgcn_readlane(pti, 0))  + ws[WS_U0 + 64];
    float uh1 = __int_as_float(__builtin_amdgcn_readlane(pti, 16)) + ws[WS_U0 + 65];
    float uh2 = __int_as_float(__builtin_amdgcn_readlane(pti, 32)) + ws[WS_U0 + 66];
    float uh3 = __int_as_float(__builtin_amdgcn_readlane(pti, 48)) + ws[WS_U0 + 67];
    rpdot = fmaf(rpa.w, uh3, fmaf(rpa.z, uh2, fmaf(rpa.y, uh1, rpa.x * uh0)));
  }
  // cterm = ego.g + c0
  float cterm;
  {
    float pc = egoR[lane] * ws[WS_G + lane];
    pc = red16(pc);
    pc += __shfl_xor(pc, 16);
    pc += __shfl_xor(pc, 32);
    cterm = pc + ws[WS_C0];
  }

  asm volatile("" ::: "memory");   // u_lds write -> read (in-wave DS order)

  // ---- phase 2: scores in (it,t4) space ----
  const float4 u4 = *(const float4*)&u_lds[wave * 64 + l * 4];
  const unsigned int mbits  = (unsigned int)__ballot(mreg != 0);
  const unsigned int mshift = mbits >> t4;   // bit 4*it = mask of m=4*it+t4

  #define SC(IT, Z) float s##IT; {                                        \
    float p = (Z).x * u4.x;                                               \
    p = fmaf((Z).y, u4.y, p);                                             \
    p = fmaf((Z).z, u4.z, p);                                             \
    p = fmaf((Z).w, u4.w, p);                                             \
    p += (l == (IT)) ? rpdot : 0.f;                                       \
    p = red16(p);                                                         \
    s##IT = ((mshift >> (4*(IT))) & 1u)                                   \
          ? (p + cterm) * 0.088388347648318447f : -1e9f; }
  SC(0, z0) SC(1, z1) SC(2, z2) SC(3, z3)
  SC(4, z4) SC(5, z5) SC(6, z6) SC(7, z7)
  #undef SC

  // softmax over 32 m's: 8 in-lane + cross-group (xor16, xor32)
  float mx = fmaxf(fmaxf(fmaxf(s0, s1), fmaxf(s2, s3)),
                   fmaxf(fmaxf(s4, s5), fmaxf(s6, s7)));
  mx = fmaxf(mx, __shfl_xor(mx, 16));
  mx = fmaxf(mx, __shfl_xor(mx, 32));
  float e0 = __expf(s0 - mx), e1 = __expf(s1 - mx);
  float e2 = __expf(s2 - mx), e3 = __expf(s3 - mx);
  float e4 = __expf(s4 - mx), e5 = __expf(s5 - mx);
  float e6 = __expf(s6 - mx), e7 = __expf(s7 - mx);
  float se = ((e0 + e1) + (e2 + e3)) + ((e4 + e5) + (e6 + e7));
  se += __shfl_xor(se, 16);
  se += __shfl_xor(se, 32);
  const float rse = __builtin_amdgcn_rcpf(se);
  const float w0 = e0 * rse, w1 = e1 * rse, w2 = e2 * rse, w3 = e3 * rse;
  const float w4 = e4 * rse, w5 = e5 * rse, w6 = e6 * rse, w7 = e7 * rse;

  // ---- phase 3: fbar[4l+k] — weights already in-lane, no broadcast ----
  float p40 = 0.f, p41 = 0.f, p42 = 0.f, p43 = 0.f;
  #define FB(W, Z) do {                                                   \
    p40 = fmaf((W), (Z).x, p40);                                          \
    p41 = fmaf((W), (Z).y, p41);                                          \
    p42 = fmaf((W), (Z).z, p42);                                          \
    p43 = fmaf((W), (Z).w, p43);                                          \
  } while (0);
  FB(w0, z0) FB(w1, z1) FB(w2, z2) FB(w3, z3)
  FB(w4, z4) FB(w5, z5) FB(w6, z6) FB(w7, z7)
  #undef FB
  p40 += __shfl_xor(p40, 16);  p40 += __shfl_xor(p40, 32);
  p41 += __shfl_xor(p41, 16);  p41 += __shfl_xor(p41, 32);
  p42 += __shfl_xor(p42, 16);  p42 += __shfl_xor(p42, 32);
  p43 += __shfl_xor(p43, 16);  p43 += __shfl_xor(p43, 32);
  if (lane < 16) {
    float4 fv; fv.x = p40; fv.y = p41; fv.z = p42; fv.w = p43;
    *(float4*)&fb_lds[wave * 64 + l * 4] = fv;
  }

  // rp tail: fbar[64+k] = sum_m w_m*rp[m][k]. This lane's rpa row m=4*(l&7)+t4
  // pairs with its own w_{l&7}; each m counted twice -> fold 0.5 into weight.
  float wsel;
  {
    float a0 = (l & 1) ? w1 : w0, a1 = (l & 1) ? w3 : w2;
    float a2 = (l & 1) ? w5 : w4, a3 = (l & 1) ? w7 : w6;
    float b0 = (l & 2) ? a1 : a0, b1 = (l & 2) ? a3 : a2;
    wsel = 0.5f * ((l & 4) ? b1 : b0);
  }
  float pr0 = wsel * rpa.x, pr1 = wsel * rpa.y;
  float pr2 = wsel * rpa.z, pr3 = wsel * rpa.w;
  pr0 = red16(pr0); pr0 += __shfl_xor(pr0, 16); pr0 += __shfl_xor(pr0, 32);
  pr1 = red16(pr1); pr1 += __shfl_xor(pr1, 16); pr1 += __shfl_xor(pr1, 32);
  pr2 = red16(pr2); pr2 += __shfl_xor(pr2, 16); pr2 += __shfl_xor(pr2, 32);
  pr3 = red16(pr3); pr3 += __shfl_xor(pr3, 16); pr3 += __shfl_xor(pr3, 32);

  asm volatile("" ::: "memory");   // fb_lds write -> read

  // ---- phase 4: out[j] = fbar @ Wvo + outb, lane = j (Wvo4 from LDS) ----
  float oa0 = 0.f, oa1 = 0.f, oa2 = 0.f, oa3 = 0.f;
  #pragma unroll 8
  for (int d4 = 0; d4 < 16; ++d4) {
    const float4 wv = *(const float4*)&cst[CST_WVO + ((d4 * IDIM + lane) << 2)];
    const float4 fv = *(const float4*)&fb_lds[wave * 64 + d4 * 4]; // broadcast
    oa0 = fmaf(fv.x, wv.x, oa0);
    oa1 = fmaf(fv.y, wv.y, oa1);
    oa2 = fmaf(fv.z, wv.z, oa2);
    oa3 = fmaf(fv.w, wv.w, oa3);
  }
  {
    const float4 wv = *(const float4*)&cst[CST_WVO + ((16 * IDIM + lane) << 2)];
    oa0 = fmaf(pr0, wv.x, oa0);
    oa1 = fmaf(pr1, wv.y, oa1);
    oa2 = fmaf(pr2, wv.z, oa2);
    oa3 = fmaf(pr3, wv.w, oa3);
  }
  out[(size_t)row * IDIM + lane] = ((oa0 + oa1) + (oa2 + oa3)) + ws[WS_OUTB + lane];
}

extern "C" void kernel_launch(void* const* d_in, const int* in_sizes, int n_in,
                              void* d_out, int out_size, void* d_ws, size_t ws_size,
                              hipStream_t stream) {
  const float* ego = (const float*)d_in[0];
  const float* nz  = (const float*)d_in[1];
  const float* rp  = (const float*)d_in[2];
  const int*   mk  = (const int*)d_in[3];
  const float* Wq  = (const float*)d_in[4];
  const float* bq  = (const float*)d_in[5];
  const float* Wk  = (const float*)d_in[6];
  const float* bk  = (const float*)d_in[7];
  const float* Wv  = (const float*)d_in[8];
  const float* bv  = (const float*)d_in[9];
  const float* Wo  = (const float*)d_in[10];
  const float* bo  = (const float*)d_in[11];
  float* ws = (float*)d_ws;   // needs WS_FLOATS*4 = 35616 bytes
  float* o  = (float*)d_out;

  const int nrows = in_sizes[0] / IDIM;   // 16384

  ga_precompute<<<(PRE_T + 255) / 256, 256, 0, stream>>>(
      Wq, bq, Wk, bk, Wv, bv, Wo, bo, ws);
  ga_main<<<nrows / 8, 512, 0, stream>>>(ego, nz, rp, mk, ws, o);
}